// Round 6
// baseline (1141.627 us; speedup 1.0000x reference)
//
#include <hip/hip_runtime.h>
#include <cstddef>

// Problem constants (match reference init_kwargs)
#define N_PTS 9216          // 96^2 grid points
#define KDIM  256           // flattened image dim (1*16*16)
#define PGRID 96
#define NS    9             // int(96*0.1)
// analytic mask: pos = 1/360, neg = -0.5/8855, diag = 0
// (count_pos = 19^2-1 = 360 ; sum_neg_abs = 9216-1-360 = 8855)

#define BM 128
#define BK 32
#define NCHUNK (KDIM / BK)                 // 8
#define TILES (N_PTS / BM)                 // 72
#define NBLK  (TILES * (TILES + 1) / 2)    // 2628 lower-triangle tiles

typedef __attribute__((ext_vector_type(4))) float f32x4;

// ---------------------------------------------------------------------------
// init: zero the scalar accumulator (d_ws is poisoned 0xAA before every call)
// ---------------------------------------------------------------------------
__global__ void PeriodicGridRegularization_71640054497944_init(float* __restrict__ acc) {
    if (threadIdx.x == 0 && blockIdx.x == 0) acc[0] = 0.0f;
}

// ---------------------------------------------------------------------------
// main: fp32 pairwise squared distances (diff^2 form), 128x128 lower-triangle
// tiles, fused dist -> softplus -> analytic mask -> reduction -> atomicAdd.
// 256 threads as 16x16; each thread owns an 8x8 sub-tile.
// Structure identical to the round-4 kernel (proven to execute); only the
// input decode changed: x is float32, staged directly into LDS.
// ---------------------------------------------------------------------------
__global__ __launch_bounds__(256) void PeriodicGridRegularization_71640054497944_kernel(
        const float* __restrict__ x,   // images fp32 [9216][256]
        float* __restrict__ acc) {
    __shared__ float As[BK][BM + 1];   // k-major, +1 pad
    __shared__ float Bs[BK][BM + 1];
    __shared__ float red[4];

    const int tid = threadIdx.x;
    const int tx  = tid & 15;          // col group 0..15
    const int ty  = tid >> 4;          // row group 0..15

    // decode linear block id -> (bi, bj), bj <= bi
    const int bid = (int)blockIdx.x;
    int bi = (int)((sqrtf(8.0f * (float)bid + 1.0f) - 1.0f) * 0.5f);
    if (bi > TILES - 1) bi = TILES - 1;
    while ((bi + 1) * (bi + 2) / 2 <= bid) ++bi;
    while (bi * (bi + 1) / 2 > bid) --bi;
    const int bj = bid - bi * (bi + 1) / 2;
    const int rowA0 = bi * BM;
    const int rowB0 = bj * BM;

    float dacc[8][8];
#pragma unroll
    for (int i = 0; i < 8; ++i)
#pragma unroll
        for (int j = 0; j < 8; ++j) dacc[i][j] = 0.0f;

    const int sr    = tid >> 1;   // staging row 0..127
    const int shalf = tid & 1;    // which 16-float half of the 32-wide chunk

    for (int kt = 0; kt < NCHUNK; ++kt) {
        // each thread loads 16 floats (4 x float4) of one A row and one B row
        f32x4 va[4], vb[4];
        const float* pa = x + (size_t)(rowA0 + sr) * KDIM + kt * BK + shalf * 16;
        const float* pb = x + (size_t)(rowB0 + sr) * KDIM + kt * BK + shalf * 16;
#pragma unroll
        for (int q = 0; q < 4; ++q) {
            va[q] = *(const f32x4*)(pa + q * 4);
            vb[q] = *(const f32x4*)(pb + q * 4);
        }
        __syncthreads();          // previous iteration's LDS reads done
#pragma unroll
        for (int q = 0; q < 4; ++q)
#pragma unroll
            for (int e = 0; e < 4; ++e) {
                const int k = shalf * 16 + q * 4 + e;   // local k within chunk
                As[k][sr] = va[q][e];
                Bs[k][sr] = vb[q][e];
            }
        __syncthreads();          // staging visible

#pragma unroll
        for (int k = 0; k < BK; ++k) {
            float a[8], b[8];
#pragma unroll
            for (int i = 0; i < 8; ++i) a[i] = As[k][ty * 8 + i];
#pragma unroll
            for (int j = 0; j < 8; ++j) b[j] = Bs[k][tx * 8 + j];
#pragma unroll
            for (int i = 0; i < 8; ++i)
#pragma unroll
                for (int j = 0; j < 8; ++j) {
                    const float d = a[i] - b[j];
                    dacc[i][j] = fmaf(d, d, dacc[i][j]);
                }
        }
    }

    // epilogue: dist -> stable softplus -> sim -> analytic mask weight
    const float WPOS = 1.0f / 360.0f;
    const float WNEG = -0.5f / 8855.0f;
    float part = 0.0f;
#pragma unroll
    for (int i = 0; i < 8; ++i) {
        const int gi = rowA0 + ty * 8 + i;
        const int i0 = gi / PGRID;
        const int i1 = gi - i0 * PGRID;
#pragma unroll
        for (int j = 0; j < 8; ++j) {
            const int gj = rowB0 + tx * 8 + j;
            const int j0 = gj / PGRID;
            const int j1 = gj - j0 * PGRID;

            const float d2   = fmaxf(dacc[i][j], 0.0f);
            const float dist = sqrtf(d2);
            const float z    = fmaf(-5.0f, dist, 5.0f);            // 5*(1-dist)
            const float e    = __expf(-fabsf(z));
            const float sp   = fmaxf(z, 0.0f) + __logf(1.0f + e);  // stable softplus
            const float sim  = fmaf(0.4f, sp, -1.0027f);           // 2*sp/5 - 1.0027

            int dr = i0 - j0; dr = dr < 0 ? -dr : dr; { const int t = PGRID - dr; dr = dr < t ? dr : t; }
            int dc = i1 - j1; dc = dc < 0 ? -dc : dc; { const int t = PGRID - dc; dc = dc < t ? dc : t; }
            const float w = (gi == gj) ? 0.0f
                          : ((dr <= NS && dc <= NS) ? WPOS : WNEG);
            part = fmaf(w, sim, part);
        }
    }
    if (bi != bj) part *= 2.0f;   // symmetric counterpart tile

#pragma unroll
    for (int off = 32; off > 0; off >>= 1) part += __shfl_down(part, off, 64);
    if ((tid & 63) == 0) red[tid >> 6] = part;
    __syncthreads();
    if (tid == 0) atomicAdd(acc, red[0] + red[1] + red[2] + red[3]);
}

// ---------------------------------------------------------------------------
// finalize: v = acc/N. Dual-format write: low 16 bits = RNE bf16(v) bits
// (the confirmed output format); full word also decodes as fp32 ~= v in case
// the output is ever read as float32. Proven readable in rounds 4/5.
// ---------------------------------------------------------------------------
__global__ void PeriodicGridRegularization_71640054497944_fin(const float* __restrict__ acc,
                                                              unsigned int* __restrict__ out) {
    if (threadIdx.x == 0 && blockIdx.x == 0) {
        union { float f; unsigned int u; } w;
        w.f = acc[0] * (1.0f / (float)N_PTS);
        const unsigned int b = (w.u + 0x7FFFu + ((w.u >> 16) & 1u)) >> 16;  // RNE bf16 bits
        out[0] = (b << 16) | b;
    }
}

extern "C" void kernel_launch(void* const* d_in, const int* in_sizes, int n_in,
                              void* d_out, int out_size, void* d_ws, size_t ws_size,
                              hipStream_t stream) {
    const float* x = (const float*)d_in[0];   // images, float32 [9216,256]
    // d_in[1] (neighbor_mask, float32) is analytic -> recomputed in-register, never read.
    float* acc = (float*)d_ws;                // single fp32 accumulator

    PeriodicGridRegularization_71640054497944_init<<<1, 64, 0, stream>>>(acc);
    PeriodicGridRegularization_71640054497944_kernel<<<NBLK, 256, 0, stream>>>(x, acc);
    PeriodicGridRegularization_71640054497944_fin<<<1, 64, 0, stream>>>(acc, (unsigned int*)d_out);
}

// Round 7
// 457.117 us; speedup vs baseline: 2.4975x; 2.4975x over previous
//
#include <hip/hip_runtime.h>
#include <cstddef>

// Problem constants (match reference init_kwargs)
#define N_PTS 9216          // 96^2 grid points
#define KDIM  256           // flattened image dim (1*16*16)
#define PGRID 96
#define NS    9             // int(96*0.1)
// analytic mask: pos = 1/360, neg = -0.5/8855, diag = 0

#define BM 128
#define BK 32
#define NKT (KDIM / BK)                    // 8
#define TILES (N_PTS / BM)                 // 72
#define NBLK  (TILES * (TILES + 1) / 2)    // 2628 lower-triangle tiles

typedef __attribute__((ext_vector_type(8))) __bf16         bf16x8; // MFMA A/B (V8y)
typedef __attribute__((ext_vector_type(4))) float          f32x4;
typedef __attribute__((ext_vector_type(4))) unsigned int   u32x4;
typedef __attribute__((ext_vector_type(4))) unsigned short u16x4;

__device__ __forceinline__ float bf2f(unsigned short b) {
    union { unsigned int u; float f; } v;
    v.u = ((unsigned int)b) << 16;
    return v.f;
}
__device__ __forceinline__ unsigned short f2bf_rne(float f) {
    union { float f; unsigned int u; } w; w.f = f;
    return (unsigned short)((w.u + 0x7FFFu + ((w.u >> 16) & 1u)) >> 16);
}

// ---------------------------------------------------------------------------
// prep: fp32 -> bf16 copy (RNE), fp32 row sums of squares, zero accumulator.
// One wave per row (4 elems/lane). 2304 blocks x 256.
// ---------------------------------------------------------------------------
__global__ __launch_bounds__(256) void PeriodicGridRegularization_71640054497944_prep(
        const float* __restrict__ x, unsigned short* __restrict__ xb,
        float* __restrict__ sqv, float* __restrict__ acc) {
    const int lane = threadIdx.x & 63;
    const int row  = (int)((blockIdx.x * blockDim.x + threadIdx.x) >> 6);
    const f32x4 v  = *(const f32x4*)(x + (size_t)row * KDIM + lane * 4);
    float s = 0.0f;
    u16x4 o;
#pragma unroll
    for (int e = 0; e < 4; ++e) { s = fmaf(v[e], v[e], s); o[e] = f2bf_rne(v[e]); }
    *(u16x4*)(xb + (size_t)row * KDIM + lane * 4) = o;
#pragma unroll
    for (int off = 32; off > 0; off >>= 1) s += __shfl_down(s, off, 64);
    if (lane == 0) sqv[row] = s;
    if (blockIdx.x == 0 && threadIdx.x == 0) acc[0] = 0.0f;
}

// ---------------------------------------------------------------------------
// gram_mfma: 128x128 lower-triangle Gram tiles via bf16 MFMA, fused
// dist -> softplus -> analytic mask -> reduction -> atomicAdd.
// 4 waves: wave (wm,wn) owns a 64x64 slab as 4x4 16x16 fragments.
// ---------------------------------------------------------------------------
__global__ __launch_bounds__(256) void PeriodicGridRegularization_71640054497944_gram(
        const unsigned short* __restrict__ xb,   // bf16 bits [9216][256]
        const float* __restrict__ sqv,           // fp32 row norms^2
        float* __restrict__ acc) {
    __shared__ unsigned short As[BM * BK];   // 8 KB, row-major (row stride 32)
    __shared__ unsigned short Bs[BM * BK];   // 8 KB
    __shared__ float red[4];

    const int tid  = threadIdx.x;
    const int lane = tid & 63;
    const int wid  = tid >> 6;
    const int wm   = wid >> 1;
    const int wn   = wid & 1;

    // decode linear block id -> (bi, bj), bj <= bi  (proven in round 6)
    const int bid = (int)blockIdx.x;
    int bi = (int)((sqrtf(8.0f * (float)bid + 1.0f) - 1.0f) * 0.5f);
    if (bi > TILES - 1) bi = TILES - 1;
    while ((bi + 1) * (bi + 2) / 2 <= bid) ++bi;
    while (bi * (bi + 1) / 2 > bid) --bi;
    const int bj = bid - bi * (bi + 1) / 2;
    const int rowA0 = bi * BM;
    const int rowB0 = bj * BM;

    f32x4 c[4][4];
#pragma unroll
    for (int i = 0; i < 4; ++i)
#pragma unroll
        for (int j = 0; j < 4; ++j)
#pragma unroll
            for (int e = 0; e < 4; ++e) c[i][j][e] = 0.0f;

    const int krow = (lane >> 4) * 8;   // this lane's k-offset within BK

    for (int kt = 0; kt < NKT; ++kt) {
        // register-stage 16B chunks: 512 per matrix, thread t takes t and t+256
        u32x4 va[2], vb[2];
#pragma unroll
        for (int t = 0; t < 2; ++t) {
            const int s  = t * 256 + tid;
            const int r  = s >> 2;             // tile row 0..127
            const int ch = s & 3;              // 16B chunk within 32-elem row
            va[t] = *(const u32x4*)(xb + (size_t)(rowA0 + r) * KDIM + kt * BK + ch * 8);
            vb[t] = *(const u32x4*)(xb + (size_t)(rowB0 + r) * KDIM + kt * BK + ch * 8);
        }
        __syncthreads();   // previous iteration's LDS reads complete
#pragma unroll
        for (int t = 0; t < 2; ++t) {
            const int s = t * 256 + tid;
            *(u32x4*)(As + s * 8) = va[t];
            *(u32x4*)(Bs + s * 8) = vb[t];
        }
        __syncthreads();   // staging visible

#if defined(__gfx950__) && __has_builtin(__builtin_amdgcn_mfma_f32_16x16x32_bf16)
        bf16x8 a[4], b[4];
#pragma unroll
        for (int mf = 0; mf < 4; ++mf)
            a[mf] = *(const bf16x8*)(As + (wm * 64 + mf * 16 + (lane & 15)) * BK + krow);
#pragma unroll
        for (int nf = 0; nf < 4; ++nf)
            b[nf] = *(const bf16x8*)(Bs + (wn * 64 + nf * 16 + (lane & 15)) * BK + krow);
#pragma unroll
        for (int mf = 0; mf < 4; ++mf)
#pragma unroll
            for (int nf = 0; nf < 4; ++nf)
                c[mf][nf] = __builtin_amdgcn_mfma_f32_16x16x32_bf16(a[mf], b[nf], c[mf][nf], 0, 0, 0);
#else
        // correct-anywhere scalar fallback (same C/D ownership mapping)
#pragma unroll
        for (int mf = 0; mf < 4; ++mf)
#pragma unroll
            for (int nf = 0; nf < 4; ++nf)
#pragma unroll
                for (int r = 0; r < 4; ++r) {
                    const int ml = wm * 64 + mf * 16 + (lane >> 4) * 4 + r;
                    const int nl = wn * 64 + nf * 16 + (lane & 15);
                    float s = c[mf][nf][r];
                    for (int k = 0; k < BK; ++k)
                        s = fmaf(bf2f(As[ml * BK + k]), bf2f(Bs[nl * BK + k]), s);
                    c[mf][nf][r] = s;
                }
#endif
    }

    // epilogue: d2 = sqi + sqj - 2*dot ; dist -> softplus -> sim ; analytic mask
    // C/D layout (16x16x32): col = lane&15, row = (lane>>4)*4 + reg
    const float WPOS = 1.0f / 360.0f;
    const float WNEG = -0.5f / 8855.0f;
    float part = 0.0f;
#pragma unroll
    for (int mf = 0; mf < 4; ++mf) {
#pragma unroll
        for (int r = 0; r < 4; ++r) {
            const int gi  = rowA0 + wm * 64 + mf * 16 + (lane >> 4) * 4 + r;
            const float sqi = sqv[gi];
            const int i0 = gi / PGRID;
            const int i1 = gi - i0 * PGRID;
#pragma unroll
            for (int nf = 0; nf < 4; ++nf) {
                const int gj  = rowB0 + wn * 64 + nf * 16 + (lane & 15);
                const float sqj = sqv[gj];
                const int j0 = gj / PGRID;
                const int j1 = gj - j0 * PGRID;

                const float d2   = fmaxf(fmaf(-2.0f, c[mf][nf][r], sqi + sqj), 0.0f);
                const float dist = sqrtf(d2);
                const float z    = fmaf(-5.0f, dist, 5.0f);            // 5*(1-dist)
                const float e    = __expf(-fabsf(z));
                const float sp   = fmaxf(z, 0.0f) + __logf(1.0f + e);  // stable softplus
                const float sim  = fmaf(0.4f, sp, -1.0027f);           // 2*sp/5 - 1.0027

                int dr = i0 - j0; dr = dr < 0 ? -dr : dr; { const int t = PGRID - dr; dr = dr < t ? dr : t; }
                int dc = i1 - j1; dc = dc < 0 ? -dc : dc; { const int t = PGRID - dc; dc = dc < t ? dc : t; }
                const float w = (gi == gj) ? 0.0f
                              : ((dr <= NS && dc <= NS) ? WPOS : WNEG);
                part = fmaf(w, sim, part);
            }
        }
    }
    if (bi != bj) part *= 2.0f;   // symmetric counterpart tile

#pragma unroll
    for (int off = 32; off > 0; off >>= 1) part += __shfl_down(part, off, 64);
    if (lane == 0) red[wid] = part;
    __syncthreads();
    if (tid == 0) atomicAdd(acc, red[0] + red[1] + red[2] + red[3]);
}

// ---------------------------------------------------------------------------
// Fallback VALU pipeline (round-6 kernel, proven) — used only if ws too small.
// ---------------------------------------------------------------------------
__global__ void PeriodicGridRegularization_71640054497944_init(float* __restrict__ acc) {
    if (threadIdx.x == 0 && blockIdx.x == 0) acc[0] = 0.0f;
}

__global__ __launch_bounds__(256) void PeriodicGridRegularization_71640054497944_valu(
        const float* __restrict__ x, float* __restrict__ acc) {
    __shared__ float As[BK][BM + 1];
    __shared__ float Bs[BK][BM + 1];
    __shared__ float red[4];
    const int tid = threadIdx.x;
    const int tx  = tid & 15;
    const int ty  = tid >> 4;
    const int bid = (int)blockIdx.x;
    int bi = (int)((sqrtf(8.0f * (float)bid + 1.0f) - 1.0f) * 0.5f);
    if (bi > TILES - 1) bi = TILES - 1;
    while ((bi + 1) * (bi + 2) / 2 <= bid) ++bi;
    while (bi * (bi + 1) / 2 > bid) --bi;
    const int bj = bid - bi * (bi + 1) / 2;
    const int rowA0 = bi * BM, rowB0 = bj * BM;
    float dacc[8][8];
#pragma unroll
    for (int i = 0; i < 8; ++i)
#pragma unroll
        for (int j = 0; j < 8; ++j) dacc[i][j] = 0.0f;
    const int sr = tid >> 1, shalf = tid & 1;
    for (int kt = 0; kt < NKT; ++kt) {
        f32x4 va[4], vb[4];
        const float* pa = x + (size_t)(rowA0 + sr) * KDIM + kt * BK + shalf * 16;
        const float* pb = x + (size_t)(rowB0 + sr) * KDIM + kt * BK + shalf * 16;
#pragma unroll
        for (int q = 0; q < 4; ++q) { va[q] = *(const f32x4*)(pa + q * 4); vb[q] = *(const f32x4*)(pb + q * 4); }
        __syncthreads();
#pragma unroll
        for (int q = 0; q < 4; ++q)
#pragma unroll
            for (int e = 0; e < 4; ++e) {
                const int k = shalf * 16 + q * 4 + e;
                As[k][sr] = va[q][e];
                Bs[k][sr] = vb[q][e];
            }
        __syncthreads();
#pragma unroll
        for (int k = 0; k < BK; ++k) {
            float a[8], b[8];
#pragma unroll
            for (int i = 0; i < 8; ++i) a[i] = As[k][ty * 8 + i];
#pragma unroll
            for (int j = 0; j < 8; ++j) b[j] = Bs[k][tx * 8 + j];
#pragma unroll
            for (int i = 0; i < 8; ++i)
#pragma unroll
                for (int j = 0; j < 8; ++j) { const float d = a[i] - b[j]; dacc[i][j] = fmaf(d, d, dacc[i][j]); }
        }
    }
    const float WPOS = 1.0f / 360.0f, WNEG = -0.5f / 8855.0f;
    float part = 0.0f;
#pragma unroll
    for (int i = 0; i < 8; ++i) {
        const int gi = rowA0 + ty * 8 + i;
        const int i0 = gi / PGRID, i1 = gi - i0 * PGRID;
#pragma unroll
        for (int j = 0; j < 8; ++j) {
            const int gj = rowB0 + tx * 8 + j;
            const int j0 = gj / PGRID, j1 = gj - j0 * PGRID;
            const float d2 = fmaxf(dacc[i][j], 0.0f);
            const float dist = sqrtf(d2);
            const float z = fmaf(-5.0f, dist, 5.0f);
            const float e = __expf(-fabsf(z));
            const float sp = fmaxf(z, 0.0f) + __logf(1.0f + e);
            const float sim = fmaf(0.4f, sp, -1.0027f);
            int dr = i0 - j0; dr = dr < 0 ? -dr : dr; { const int t = PGRID - dr; dr = dr < t ? dr : t; }
            int dc = i1 - j1; dc = dc < 0 ? -dc : dc; { const int t = PGRID - dc; dc = dc < t ? dc : t; }
            const float w = (gi == gj) ? 0.0f : ((dr <= NS && dc <= NS) ? WPOS : WNEG);
            part = fmaf(w, sim, part);
        }
    }
    if (bi != bj) part *= 2.0f;
#pragma unroll
    for (int off = 32; off > 0; off >>= 1) part += __shfl_down(part, off, 64);
    if ((tid & 63) == 0) red[tid >> 6] = part;
    __syncthreads();
    if (tid == 0) atomicAdd(acc, red[0] + red[1] + red[2] + red[3]);
}

// ---------------------------------------------------------------------------
// finalize: v = acc/N; dual-format write (low16 = RNE bf16 bits). Proven.
// ---------------------------------------------------------------------------
__global__ void PeriodicGridRegularization_71640054497944_fin(const float* __restrict__ acc,
                                                              unsigned int* __restrict__ out) {
    if (threadIdx.x == 0 && blockIdx.x == 0) {
        union { float f; unsigned int u; } w;
        w.f = acc[0] * (1.0f / (float)N_PTS);
        const unsigned int b = (w.u + 0x7FFFu + ((w.u >> 16) & 1u)) >> 16;
        out[0] = (b << 16) | b;
    }
}

extern "C" void kernel_launch(void* const* d_in, const int* in_sizes, int n_in,
                              void* d_out, int out_size, void* d_ws, size_t ws_size,
                              hipStream_t stream) {
    const float* x = (const float*)d_in[0];   // images, float32 [9216,256]
    // d_in[1] (neighbor_mask) is analytic -> recomputed in-register, never read.
    const size_t xb_bytes = (size_t)N_PTS * KDIM * 2;          // 4.72 MB bf16 copy
    const size_t need     = xb_bytes + (size_t)N_PTS * 4 + 64;

    if (ws_size >= need) {
        unsigned short* xb  = (unsigned short*)d_ws;
        float*          sqv = (float*)((char*)d_ws + xb_bytes);
        float*          acc = sqv + N_PTS;
        PeriodicGridRegularization_71640054497944_prep<<<N_PTS / 4, 256, 0, stream>>>(x, xb, sqv, acc);
        PeriodicGridRegularization_71640054497944_gram<<<NBLK, 256, 0, stream>>>(xb, sqv, acc);
        PeriodicGridRegularization_71640054497944_fin<<<1, 64, 0, stream>>>(acc, (unsigned int*)d_out);
    } else {
        float* acc = (float*)d_ws;
        PeriodicGridRegularization_71640054497944_init<<<1, 64, 0, stream>>>(acc);
        PeriodicGridRegularization_71640054497944_valu<<<NBLK, 256, 0, stream>>>(x, acc);
        PeriodicGridRegularization_71640054497944_fin<<<1, 64, 0, stream>>>(acc, (unsigned int*)d_out);
    }
}

// Round 8
// 416.924 us; speedup vs baseline: 2.7382x; 1.0964x over previous
//
#include <hip/hip_runtime.h>
#include <cstddef>

// Problem constants (match reference init_kwargs)
#define N_PTS 9216          // 96^2 grid points
#define KDIM  256           // flattened image dim (1*16*16)
#define PGRID 96
#define NS    9             // int(96*0.1)
// analytic mask: pos = 1/360, neg = -0.5/8855, diag = 0
// torus => every point has exactly 360 neighbors => row-sum(w) = 1 - 0.5 = 0.5

#define BM 128
#define BK 32
#define NKT (KDIM / BK)                    // 8
#define TILES (N_PTS / BM)                 // 72
#define NBLK  (TILES * (TILES + 1) / 2)    // 2628 lower-triangle tiles

#define GUARD_T 100.0f      // d2 below this => softplus not saturated (dist<10, z<-45)
#define SIM_SAT (-1.0027f)  // sim value when softplus fully saturated

typedef __attribute__((ext_vector_type(8))) __bf16         bf16x8; // MFMA A/B (V8y)
typedef __attribute__((ext_vector_type(4))) float          f32x4;
typedef __attribute__((ext_vector_type(4))) unsigned int   u32x4;
typedef __attribute__((ext_vector_type(4))) unsigned short u16x4;

__device__ __forceinline__ float bf2f(unsigned short b) {
    union { unsigned int u; float f; } v;
    v.u = ((unsigned int)b) << 16;
    return v.f;
}
__device__ __forceinline__ unsigned short f2bf_rne(float f) {
    union { float f; unsigned int u; } w; w.f = f;
    return (unsigned short)((w.u + 0x7FFFu + ((w.u >> 16) & 1u)) >> 16);
}

// ---------------------------------------------------------------------------
// prep: fp32 -> bf16 copy (RNE), fp32 row sums of squares, zero accumulator.
// ---------------------------------------------------------------------------
__global__ __launch_bounds__(256) void PeriodicGridRegularization_71640054497944_prep(
        const float* __restrict__ x, unsigned short* __restrict__ xb,
        float* __restrict__ sqv, float* __restrict__ acc) {
    const int lane = threadIdx.x & 63;
    const int row  = (int)((blockIdx.x * blockDim.x + threadIdx.x) >> 6);
    const f32x4 v  = *(const f32x4*)(x + (size_t)row * KDIM + lane * 4);
    float s = 0.0f;
    u16x4 o;
#pragma unroll
    for (int e = 0; e < 4; ++e) { s = fmaf(v[e], v[e], s); o[e] = f2bf_rne(v[e]); }
    *(u16x4*)(xb + (size_t)row * KDIM + lane * 4) = o;
#pragma unroll
    for (int off = 32; off > 0; off >>= 1) s += __shfl_down(s, off, 64);
    if (lane == 0) sqv[row] = s;
    if (blockIdx.x == 0 && threadIdx.x == 0) acc[0] = 0.0f;
}

// ---------------------------------------------------------------------------
// gram: 128x128 lower-triangle Gram tiles via bf16 MFMA. Epilogue is now a
// GUARD: softplus is saturated (sim == SIM_SAT) whenever d2 >= GUARD_T, and
// sum(w) over the torus is analytic (0.5 per row), so the fast path only
// tracks min off-diagonal d2. A (normally never-taken) slow path adds the
// exact correction w*0.4*softplus(z) for any element with d2 < GUARD_T,
// keeping the kernel exact for arbitrary inputs.
// ---------------------------------------------------------------------------
__global__ __launch_bounds__(256) void PeriodicGridRegularization_71640054497944_gram(
        const unsigned short* __restrict__ xb,   // bf16 bits [9216][256]
        const float* __restrict__ sqv,           // fp32 row norms^2
        float* __restrict__ acc) {
    __shared__ unsigned short As[BM * BK];   // 8 KB, row-major (row stride 32)
    __shared__ unsigned short Bs[BM * BK];   // 8 KB
    __shared__ float red[4];

    const int tid  = threadIdx.x;
    const int lane = tid & 63;
    const int wid  = tid >> 6;
    const int wm   = wid >> 1;
    const int wn   = wid & 1;

    // decode linear block id -> (bi, bj), bj <= bi  (proven R6/R7)
    const int bid = (int)blockIdx.x;
    int bi = (int)((sqrtf(8.0f * (float)bid + 1.0f) - 1.0f) * 0.5f);
    if (bi > TILES - 1) bi = TILES - 1;
    while ((bi + 1) * (bi + 2) / 2 <= bid) ++bi;
    while (bi * (bi + 1) / 2 > bid) --bi;
    const int bj = bid - bi * (bi + 1) / 2;
    const int rowA0 = bi * BM;
    const int rowB0 = bj * BM;

    f32x4 c[4][4];
#pragma unroll
    for (int i = 0; i < 4; ++i)
#pragma unroll
        for (int j = 0; j < 4; ++j)
#pragma unroll
            for (int e = 0; e < 4; ++e) c[i][j][e] = 0.0f;

    const int krow = (lane >> 4) * 8;

    for (int kt = 0; kt < NKT; ++kt) {
        u32x4 va[2], vb[2];
#pragma unroll
        for (int t = 0; t < 2; ++t) {
            const int s  = t * 256 + tid;
            const int r  = s >> 2;
            const int ch = s & 3;
            va[t] = *(const u32x4*)(xb + (size_t)(rowA0 + r) * KDIM + kt * BK + ch * 8);
            vb[t] = *(const u32x4*)(xb + (size_t)(rowB0 + r) * KDIM + kt * BK + ch * 8);
        }
        __syncthreads();
#pragma unroll
        for (int t = 0; t < 2; ++t) {
            const int s = t * 256 + tid;
            *(u32x4*)(As + s * 8) = va[t];
            *(u32x4*)(Bs + s * 8) = vb[t];
        }
        __syncthreads();

#if defined(__gfx950__) && __has_builtin(__builtin_amdgcn_mfma_f32_16x16x32_bf16)
        bf16x8 a[4], b[4];
#pragma unroll
        for (int mf = 0; mf < 4; ++mf)
            a[mf] = *(const bf16x8*)(As + (wm * 64 + mf * 16 + (lane & 15)) * BK + krow);
#pragma unroll
        for (int nf = 0; nf < 4; ++nf)
            b[nf] = *(const bf16x8*)(Bs + (wn * 64 + nf * 16 + (lane & 15)) * BK + krow);
#pragma unroll
        for (int mf = 0; mf < 4; ++mf)
#pragma unroll
            for (int nf = 0; nf < 4; ++nf)
                c[mf][nf] = __builtin_amdgcn_mfma_f32_16x16x32_bf16(a[mf], b[nf], c[mf][nf], 0, 0, 0);
#else
#pragma unroll
        for (int mf = 0; mf < 4; ++mf)
#pragma unroll
            for (int nf = 0; nf < 4; ++nf)
#pragma unroll
                for (int r = 0; r < 4; ++r) {
                    const int ml = wm * 64 + mf * 16 + (lane >> 4) * 4 + r;
                    const int nl = wn * 64 + nf * 16 + (lane & 15);
                    float s = c[mf][nf][r];
                    for (int k = 0; k < BK; ++k)
                        s = fmaf(bf2f(As[ml * BK + k]), bf2f(Bs[nl * BK + k]), s);
                    c[mf][nf][r] = s;
                }
#endif
    }

    // ---------------- guard epilogue ----------------
    // C/D layout (16x16x32): col = lane&15, row = (lane>>4)*4 + reg
    float sqi[4];   // per mf-fragment row base (r adds +1 each)
    float sqj[4];
#pragma unroll
    for (int nf = 0; nf < 4; ++nf) sqj[nf] = sqv[rowB0 + wn * 64 + nf * 16 + (lane & 15)];

    const bool dt = (bi == bj);
    const int  li = (lane >> 4) * 4;   // row sub-offset base
    const int  lj = lane & 15;

    float mind2 = 1e30f;
#pragma unroll
    for (int mf = 0; mf < 4; ++mf) {
#pragma unroll
        for (int r = 0; r < 4; ++r) {
            const int gi = rowA0 + wm * 64 + mf * 16 + li + r;
            const float si = sqv[gi];
#pragma unroll
            for (int nf = 0; nf < 4; ++nf) {
                const float d2 = fmaf(-2.0f, c[mf][nf][r], si + sqj[nf]);
                const int gj = rowB0 + wn * 64 + nf * 16 + lj;
                const float d2t = (dt && gi == gj) ? 1e30f : d2;
                mind2 = fminf(mind2, d2t);
            }
        }
    }

    float part = 0.0f;
    if (__any(mind2 < GUARD_T)) {
        // exact correction path (never taken for this data; exact for any data)
        const float WPOS = 1.0f / 360.0f;
        const float WNEG = -0.5f / 8855.0f;
#pragma unroll
        for (int mf = 0; mf < 4; ++mf) {
#pragma unroll
            for (int r = 0; r < 4; ++r) {
                const int gi = rowA0 + wm * 64 + mf * 16 + li + r;
                const float si = sqv[gi];
                const int i0 = gi / PGRID;
                const int i1 = gi - i0 * PGRID;
#pragma unroll
                for (int nf = 0; nf < 4; ++nf) {
                    const int gj = rowB0 + wn * 64 + nf * 16 + lj;
                    const float d2 = fmaf(-2.0f, c[mf][nf][r], si + sqj[nf]);
                    if (!(dt && gi == gj) && d2 < GUARD_T) {
                        const float dist = sqrtf(fmaxf(d2, 0.0f));
                        const float z    = fmaf(-5.0f, dist, 5.0f);
                        const float e    = __expf(-fabsf(z));
                        const float sp   = fmaxf(z, 0.0f) + __logf(1.0f + e);
                        // correction vs saturated assumption: w * (sim - SIM_SAT) = w * 0.4 * sp
                        const int j0 = gj / PGRID;
                        const int j1 = gj - j0 * PGRID;
                        int dr = i0 - j0; dr = dr < 0 ? -dr : dr; { const int t = PGRID - dr; dr = dr < t ? dr : t; }
                        int dc = i1 - j1; dc = dc < 0 ? -dc : dc; { const int t = PGRID - dc; dc = dc < t ? dc : t; }
                        const float w = (dr <= NS && dc <= NS) ? WPOS : WNEG;
                        part = fmaf(w * 0.4f, sp, part);
                    }
                }
            }
        }
    }
    if (bi != bj) part *= 2.0f;   // symmetric counterpart tile

#pragma unroll
    for (int off = 32; off > 0; off >>= 1) part += __shfl_down(part, off, 64);
    if (lane == 0) red[wid] = part;
    __syncthreads();
    if (tid == 0) atomicAdd(acc, red[0] + red[1] + red[2] + red[3]);
}

// ---------------------------------------------------------------------------
// Fallback VALU pipeline (round-6 kernel, proven) — used only if ws too small.
// ---------------------------------------------------------------------------
__global__ void PeriodicGridRegularization_71640054497944_init(float* __restrict__ acc) {
    if (threadIdx.x == 0 && blockIdx.x == 0) acc[0] = 0.0f;
}

__global__ __launch_bounds__(256) void PeriodicGridRegularization_71640054497944_valu(
        const float* __restrict__ x, float* __restrict__ acc) {
    __shared__ float As[BK][BM + 1];
    __shared__ float Bs[BK][BM + 1];
    __shared__ float red[4];
    const int tid = threadIdx.x;
    const int tx  = tid & 15;
    const int ty  = tid >> 4;
    const int bid = (int)blockIdx.x;
    int bi = (int)((sqrtf(8.0f * (float)bid + 1.0f) - 1.0f) * 0.5f);
    if (bi > TILES - 1) bi = TILES - 1;
    while ((bi + 1) * (bi + 2) / 2 <= bid) ++bi;
    while (bi * (bi + 1) / 2 > bid) --bi;
    const int bj = bid - bi * (bi + 1) / 2;
    const int rowA0 = bi * BM, rowB0 = bj * BM;
    float dacc[8][8];
#pragma unroll
    for (int i = 0; i < 8; ++i)
#pragma unroll
        for (int j = 0; j < 8; ++j) dacc[i][j] = 0.0f;
    const int sr = tid >> 1, shalf = tid & 1;
    for (int kt = 0; kt < NKT; ++kt) {
        f32x4 va[4], vb[4];
        const float* pa = x + (size_t)(rowA0 + sr) * KDIM + kt * BK + shalf * 16;
        const float* pb = x + (size_t)(rowB0 + sr) * KDIM + kt * BK + shalf * 16;
#pragma unroll
        for (int q = 0; q < 4; ++q) { va[q] = *(const f32x4*)(pa + q * 4); vb[q] = *(const f32x4*)(pb + q * 4); }
        __syncthreads();
#pragma unroll
        for (int q = 0; q < 4; ++q)
#pragma unroll
            for (int e = 0; e < 4; ++e) {
                const int k = shalf * 16 + q * 4 + e;
                As[k][sr] = va[q][e];
                Bs[k][sr] = vb[q][e];
            }
        __syncthreads();
#pragma unroll
        for (int k = 0; k < BK; ++k) {
            float a[8], b[8];
#pragma unroll
            for (int i = 0; i < 8; ++i) a[i] = As[k][ty * 8 + i];
#pragma unroll
            for (int j = 0; j < 8; ++j) b[j] = Bs[k][tx * 8 + j];
#pragma unroll
            for (int i = 0; i < 8; ++i)
#pragma unroll
                for (int j = 0; j < 8; ++j) { const float d = a[i] - b[j]; dacc[i][j] = fmaf(d, d, dacc[i][j]); }
        }
    }
    const float WPOS = 1.0f / 360.0f, WNEG = -0.5f / 8855.0f;
    float part = 0.0f;
#pragma unroll
    for (int i = 0; i < 8; ++i) {
        const int gi = rowA0 + ty * 8 + i;
        const int i0 = gi / PGRID, i1 = gi - i0 * PGRID;
#pragma unroll
        for (int j = 0; j < 8; ++j) {
            const int gj = rowB0 + tx * 8 + j;
            const int j0 = gj / PGRID, j1 = gj - j0 * PGRID;
            const float d2 = fmaxf(dacc[i][j], 0.0f);
            const float dist = sqrtf(d2);
            const float z = fmaf(-5.0f, dist, 5.0f);
            const float e = __expf(-fabsf(z));
            const float sp = fmaxf(z, 0.0f) + __logf(1.0f + e);
            const float sim = fmaf(0.4f, sp, -1.0027f);
            int dr = i0 - j0; dr = dr < 0 ? -dr : dr; { const int t = PGRID - dr; dr = dr < t ? dr : t; }
            int dc = i1 - j1; dc = dc < 0 ? -dc : dc; { const int t = PGRID - dc; dc = dc < t ? dc : t; }
            const float w = (gi == gj) ? 0.0f : ((dr <= NS && dc <= NS) ? WPOS : WNEG);
            part = fmaf(w, sim, part);
        }
    }
    if (bi != bj) part *= 2.0f;
#pragma unroll
    for (int off = 32; off > 0; off >>= 1) part += __shfl_down(part, off, 64);
    if ((tid & 63) == 0) red[tid >> 6] = part;
    __syncthreads();
    if (tid == 0) atomicAdd(acc, red[0] + red[1] + red[2] + red[3]);
}

// ---------------------------------------------------------------------------
// finalize: v = corr/N + analytic saturated base (SIM_SAT * rowsum(w) = -0.50135).
// Dual-format write (low16 = RNE bf16 bits). Proven readable.
// ---------------------------------------------------------------------------
__global__ void PeriodicGridRegularization_71640054497944_fin(const float* __restrict__ acc,
                                                              unsigned int* __restrict__ out) {
    if (threadIdx.x == 0 && blockIdx.x == 0) {
        union { float f; unsigned int u; } w;
        w.f = acc[0] * (1.0f / (float)N_PTS) + SIM_SAT * 0.5f;
        const unsigned int b = (w.u + 0x7FFFu + ((w.u >> 16) & 1u)) >> 16;
        out[0] = (b << 16) | b;
    }
}

// fin for the fallback path: acc already holds the full sum
__global__ void PeriodicGridRegularization_71640054497944_finfull(const float* __restrict__ acc,
                                                                  unsigned int* __restrict__ out) {
    if (threadIdx.x == 0 && blockIdx.x == 0) {
        union { float f; unsigned int u; } w;
        w.f = acc[0] * (1.0f / (float)N_PTS);
        const unsigned int b = (w.u + 0x7FFFu + ((w.u >> 16) & 1u)) >> 16;
        out[0] = (b << 16) | b;
    }
}

extern "C" void kernel_launch(void* const* d_in, const int* in_sizes, int n_in,
                              void* d_out, int out_size, void* d_ws, size_t ws_size,
                              hipStream_t stream) {
    const float* x = (const float*)d_in[0];   // images, float32 [9216,256]
    // d_in[1] (neighbor_mask) is analytic -> recomputed in-register, never read.
    const size_t xb_bytes = (size_t)N_PTS * KDIM * 2;
    const size_t need     = xb_bytes + (size_t)N_PTS * 4 + 64;

    if (ws_size >= need) {
        unsigned short* xb  = (unsigned short*)d_ws;
        float*          sqv = (float*)((char*)d_ws + xb_bytes);
        float*          acc = sqv + N_PTS;
        PeriodicGridRegularization_71640054497944_prep<<<N_PTS / 4, 256, 0, stream>>>(x, xb, sqv, acc);
        PeriodicGridRegularization_71640054497944_gram<<<NBLK, 256, 0, stream>>>(xb, sqv, acc);
        PeriodicGridRegularization_71640054497944_fin<<<1, 64, 0, stream>>>(acc, (unsigned int*)d_out);
    } else {
        float* acc = (float*)d_ws;
        PeriodicGridRegularization_71640054497944_init<<<1, 64, 0, stream>>>(acc);
        PeriodicGridRegularization_71640054497944_valu<<<NBLK, 256, 0, stream>>>(x, acc);
        PeriodicGridRegularization_71640054497944_finfull<<<1, 64, 0, stream>>>(acc, (unsigned int*)d_out);
    }
}

// Round 9
// 415.729 us; speedup vs baseline: 2.7461x; 1.0029x over previous
//
#include <hip/hip_runtime.h>
#include <cstddef>

// Problem constants (match reference init_kwargs)
#define N_PTS 9216          // 96^2 grid points
#define KDIM  256           // flattened image dim (1*16*16)
#define PGRID 96
#define NS    9             // int(96*0.1)
// analytic mask: pos = 1/360, neg = -0.5/8855, diag = 0
// torus => every point has exactly 360 neighbors => row-sum(w) = 1 - 0.5 = 0.5

#define BM 128
#define BK 64
#define NKT (KDIM / BK)                    // 4
#define TILES (N_PTS / BM)                 // 72
#define NBLK  (TILES * (TILES + 1) / 2)    // 2628 lower-triangle tiles

#define GUARD_T 100.0f      // d2 below this => softplus not saturated
#define SIM_SAT (-1.0027f)  // sim value when softplus fully saturated

typedef __attribute__((ext_vector_type(8))) __bf16         bf16x8; // MFMA A/B (V8y)
typedef __attribute__((ext_vector_type(4))) float          f32x4;
typedef __attribute__((ext_vector_type(4))) unsigned int   u32x4;
typedef __attribute__((ext_vector_type(4))) unsigned short u16x4;

__device__ __forceinline__ float bf2f(unsigned short b) {
    union { unsigned int u; float f; } v;
    v.u = ((unsigned int)b) << 16;
    return v.f;
}
__device__ __forceinline__ unsigned short f2bf_rne(float f) {
    union { float f; unsigned int u; } w; w.f = f;
    return (unsigned short)((w.u + 0x7FFFu + ((w.u >> 16) & 1u)) >> 16);
}

// ---------------------------------------------------------------------------
// prep: fp32 -> bf16 copy (RNE), fp32 row sums of squares, zero accumulator.
// ---------------------------------------------------------------------------
__global__ __launch_bounds__(256) void PeriodicGridRegularization_71640054497944_prep(
        const float* __restrict__ x, unsigned short* __restrict__ xb,
        float* __restrict__ sqv, float* __restrict__ acc) {
    const int lane = threadIdx.x & 63;
    const int row  = (int)((blockIdx.x * blockDim.x + threadIdx.x) >> 6);
    const f32x4 v  = *(const f32x4*)(x + (size_t)row * KDIM + lane * 4);
    float s = 0.0f;
    u16x4 o;
#pragma unroll
    for (int e = 0; e < 4; ++e) { s = fmaf(v[e], v[e], s); o[e] = f2bf_rne(v[e]); }
    *(u16x4*)(xb + (size_t)row * KDIM + lane * 4) = o;
#pragma unroll
    for (int off = 32; off > 0; off >>= 1) s += __shfl_down(s, off, 64);
    if (lane == 0) sqv[row] = s;
    if (blockIdx.x == 0 && threadIdx.x == 0) acc[0] = 0.0f;
}

// ---------------------------------------------------------------------------
// gram: 128x128 lower-triangle Gram tiles via bf16 MFMA.
// BK=64, direct global->LDS staging (gfx950), XOR-swizzled chunk placement
// (swizzle applied on the GLOBAL side so the LDS destination stays
// lane-linear per the global_load_lds wave-uniform-base constraint).
// LDS layout: row-major [row][64], 16B chunk at position p holds global
// chunk  ch = p ^ (row & 7)  -> fragment ds_read_b128 spreads over all
// 32 banks (2-way alias only = free).
// Epilogue: saturation-guard (R8, proven): fast path only tracks min d2;
// exact correction path for any element with d2 < GUARD_T.
// ---------------------------------------------------------------------------
__global__ __launch_bounds__(256) void PeriodicGridRegularization_71640054497944_gram(
        const unsigned short* __restrict__ xb,   // bf16 bits [9216][256]
        const float* __restrict__ sqv,           // fp32 row norms^2
        float* __restrict__ acc) {
    __shared__ unsigned short As[BM * BK];   // 16 KB
    __shared__ unsigned short Bs[BM * BK];   // 16 KB
    __shared__ float red[4];

    const int tid  = threadIdx.x;
    const int lane = tid & 63;
    const int wid  = tid >> 6;
    const int wm   = wid >> 1;
    const int wn   = wid & 1;

    // decode linear block id -> (bi, bj), bj <= bi  (proven R6/R7/R8)
    const int bid = (int)blockIdx.x;
    int bi = (int)((sqrtf(8.0f * (float)bid + 1.0f) - 1.0f) * 0.5f);
    if (bi > TILES - 1) bi = TILES - 1;
    while ((bi + 1) * (bi + 2) / 2 <= bid) ++bi;
    while (bi * (bi + 1) / 2 > bid) --bi;
    const int bj = bid - bi * (bi + 1) / 2;
    const int rowA0 = bi * BM;
    const int rowB0 = bj * BM;

    f32x4 c[4][4];
#pragma unroll
    for (int i = 0; i < 4; ++i)
#pragma unroll
        for (int j = 0; j < 4; ++j)
#pragma unroll
            for (int e = 0; e < 4; ++e) c[i][j][e] = 0.0f;

    const int lj = lane & 15;
    const int lg = lane >> 4;           // 16-lane group -> k-chunk index base

    for (int kt = 0; kt < NKT; ++kt) {
#if defined(__gfx950__) && __has_builtin(__builtin_amdgcn_global_load_lds) && __has_builtin(__builtin_amdgcn_mfma_f32_16x16x32_bf16)
        __syncthreads();   // previous iteration's LDS reads complete
        // 1024 chunks of 16B per tile; 4 per thread per matrix, lane-linear LDS dest
#pragma unroll
        for (int t = 0; t < 4; ++t) {
            const int s  = t * 256 + tid;       // LDS chunk id 0..1023
            const int r  = s >> 3;              // tile row
            const int p  = s & 7;               // LDS chunk position in row
            const int ch = p ^ (r & 7);         // swizzled global chunk
            const unsigned short* ga = xb + (size_t)(rowA0 + r) * KDIM + kt * BK + ch * 8;
            const unsigned short* gb = xb + (size_t)(rowB0 + r) * KDIM + kt * BK + ch * 8;
            __builtin_amdgcn_global_load_lds(
                (const __attribute__((address_space(1))) void*)ga,
                (__attribute__((address_space(3))) void*)(As + s * 8), 16, 0, 0);
            __builtin_amdgcn_global_load_lds(
                (const __attribute__((address_space(1))) void*)gb,
                (__attribute__((address_space(3))) void*)(Bs + s * 8), 16, 0, 0);
        }
        __syncthreads();   // staging visible (compiler drains vmcnt here)

#pragma unroll
        for (int ks = 0; ks < 2; ++ks) {        // two 32-wide K sub-blocks
            bf16x8 a[4], b[4];
#pragma unroll
            for (int mf = 0; mf < 4; ++mf) {
                const int r = wm * 64 + mf * 16 + lj;
                const int p = (ks * 4 + lg) ^ (r & 7);
                a[mf] = *(const bf16x8*)(As + r * BK + p * 8);
            }
#pragma unroll
            for (int nf = 0; nf < 4; ++nf) {
                const int r = wn * 64 + nf * 16 + lj;
                const int p = (ks * 4 + lg) ^ (r & 7);
                b[nf] = *(const bf16x8*)(Bs + r * BK + p * 8);
            }
#pragma unroll
            for (int mf = 0; mf < 4; ++mf)
#pragma unroll
                for (int nf = 0; nf < 4; ++nf)
                    c[mf][nf] = __builtin_amdgcn_mfma_f32_16x16x32_bf16(a[mf], b[nf], c[mf][nf], 0, 0, 0);
        }
#else
        // compile-anywhere fallback (never runs on gfx950): register staging,
        // same swizzled layout, scalar dot products.
        u32x4 va[4], vb[4];
#pragma unroll
        for (int t = 0; t < 4; ++t) {
            const int s  = t * 256 + tid;
            const int r  = s >> 3;
            const int p  = s & 7;
            const int ch = p ^ (r & 7);
            va[t] = *(const u32x4*)(xb + (size_t)(rowA0 + r) * KDIM + kt * BK + ch * 8);
            vb[t] = *(const u32x4*)(xb + (size_t)(rowB0 + r) * KDIM + kt * BK + ch * 8);
        }
        __syncthreads();
#pragma unroll
        for (int t = 0; t < 4; ++t) {
            const int s = t * 256 + tid;
            *(u32x4*)(As + s * 8) = va[t];
            *(u32x4*)(Bs + s * 8) = vb[t];
        }
        __syncthreads();
#pragma unroll
        for (int mf = 0; mf < 4; ++mf)
#pragma unroll
            for (int nf = 0; nf < 4; ++nf)
#pragma unroll
                for (int r = 0; r < 4; ++r) {
                    const int ml = wm * 64 + mf * 16 + (lane >> 4) * 4 + r;
                    const int nl = wn * 64 + nf * 16 + lj;
                    float s = c[mf][nf][r];
                    for (int k = 0; k < BK; ++k) {
                        const int pa = (k >> 3) ^ (ml & 7);
                        const int pb = (k >> 3) ^ (nl & 7);
                        s = fmaf(bf2f(As[ml * BK + pa * 8 + (k & 7)]),
                                 bf2f(Bs[nl * BK + pb * 8 + (k & 7)]), s);
                    }
                    c[mf][nf][r] = s;
                }
#endif
    }

    // ---------------- guard epilogue (R8, proven) ----------------
    // C/D layout (16x16x32): col = lane&15, row = (lane>>4)*4 + reg
    float sqj[4];
#pragma unroll
    for (int nf = 0; nf < 4; ++nf) sqj[nf] = sqv[rowB0 + wn * 64 + nf * 16 + lj];

    const bool dt = (bi == bj);
    const int  li = (lane >> 4) * 4;

    float mind2 = 1e30f;
#pragma unroll
    for (int mf = 0; mf < 4; ++mf) {
#pragma unroll
        for (int r = 0; r < 4; ++r) {
            const int gi = rowA0 + wm * 64 + mf * 16 + li + r;
            const float si = sqv[gi];
#pragma unroll
            for (int nf = 0; nf < 4; ++nf) {
                const float d2 = fmaf(-2.0f, c[mf][nf][r], si + sqj[nf]);
                const int gj = rowB0 + wn * 64 + nf * 16 + lj;
                const float d2t = (dt && gi == gj) ? 1e30f : d2;
                mind2 = fminf(mind2, d2t);
            }
        }
    }

    float part = 0.0f;
    if (__any(mind2 < GUARD_T)) {
        // exact correction path (never taken for this data; exact for any data)
        const float WPOS = 1.0f / 360.0f;
        const float WNEG = -0.5f / 8855.0f;
#pragma unroll
        for (int mf = 0; mf < 4; ++mf) {
#pragma unroll
            for (int r = 0; r < 4; ++r) {
                const int gi = rowA0 + wm * 64 + mf * 16 + li + r;
                const float si = sqv[gi];
                const int i0 = gi / PGRID;
                const int i1 = gi - i0 * PGRID;
#pragma unroll
                for (int nf = 0; nf < 4; ++nf) {
                    const int gj = rowB0 + wn * 64 + nf * 16 + lj;
                    const float d2 = fmaf(-2.0f, c[mf][nf][r], si + sqj[nf]);
                    if (!(dt && gi == gj) && d2 < GUARD_T) {
                        const float dist = sqrtf(fmaxf(d2, 0.0f));
                        const float z    = fmaf(-5.0f, dist, 5.0f);
                        const float e    = __expf(-fabsf(z));
                        const float sp   = fmaxf(z, 0.0f) + __logf(1.0f + e);
                        const int j0 = gj / PGRID;
                        const int j1 = gj - j0 * PGRID;
                        int dr = i0 - j0; dr = dr < 0 ? -dr : dr; { const int t = PGRID - dr; dr = dr < t ? dr : t; }
                        int dc = i1 - j1; dc = dc < 0 ? -dc : dc; { const int t = PGRID - dc; dc = dc < t ? dc : t; }
                        const float w = (dr <= NS && dc <= NS) ? WPOS : WNEG;
                        part = fmaf(w * 0.4f, sp, part);   // w*(sim - SIM_SAT)
                    }
                }
            }
        }
    }
    if (bi != bj) part *= 2.0f;   // symmetric counterpart tile

#pragma unroll
    for (int off = 32; off > 0; off >>= 1) part += __shfl_down(part, off, 64);
    if (lane == 0) red[wid] = part;
    __syncthreads();
    if (tid == 0) atomicAdd(acc, red[0] + red[1] + red[2] + red[3]);
}

// ---------------------------------------------------------------------------
// Fallback VALU pipeline (round-6 kernel, proven) — used only if ws too small.
// ---------------------------------------------------------------------------
__global__ void PeriodicGridRegularization_71640054497944_init(float* __restrict__ acc) {
    if (threadIdx.x == 0 && blockIdx.x == 0) acc[0] = 0.0f;
}

__global__ __launch_bounds__(256) void PeriodicGridRegularization_71640054497944_valu(
        const float* __restrict__ x, float* __restrict__ acc) {
    __shared__ float As[32][BM + 1];
    __shared__ float Bs[32][BM + 1];
    __shared__ float red[4];
    const int tid = threadIdx.x;
    const int tx  = tid & 15;
    const int ty  = tid >> 4;
    const int bid = (int)blockIdx.x;
    int bi = (int)((sqrtf(8.0f * (float)bid + 1.0f) - 1.0f) * 0.5f);
    if (bi > TILES - 1) bi = TILES - 1;
    while ((bi + 1) * (bi + 2) / 2 <= bid) ++bi;
    while (bi * (bi + 1) / 2 > bid) --bi;
    const int bj = bid - bi * (bi + 1) / 2;
    const int rowA0 = bi * BM, rowB0 = bj * BM;
    float dacc[8][8];
#pragma unroll
    for (int i = 0; i < 8; ++i)
#pragma unroll
        for (int j = 0; j < 8; ++j) dacc[i][j] = 0.0f;
    const int sr = tid >> 1, shalf = tid & 1;
    for (int kt = 0; kt < 8; ++kt) {
        f32x4 va[4], vb[4];
        const float* pa = x + (size_t)(rowA0 + sr) * KDIM + kt * 32 + shalf * 16;
        const float* pb = x + (size_t)(rowB0 + sr) * KDIM + kt * 32 + shalf * 16;
#pragma unroll
        for (int q = 0; q < 4; ++q) { va[q] = *(const f32x4*)(pa + q * 4); vb[q] = *(const f32x4*)(pb + q * 4); }
        __syncthreads();
#pragma unroll
        for (int q = 0; q < 4; ++q)
#pragma unroll
            for (int e = 0; e < 4; ++e) {
                const int k = shalf * 16 + q * 4 + e;
                As[k][sr] = va[q][e];
                Bs[k][sr] = vb[q][e];
            }
        __syncthreads();
#pragma unroll
        for (int k = 0; k < 32; ++k) {
            float a[8], b[8];
#pragma unroll
            for (int i = 0; i < 8; ++i) a[i] = As[k][ty * 8 + i];
#pragma unroll
            for (int j = 0; j < 8; ++j) b[j] = Bs[k][tx * 8 + j];
#pragma unroll
            for (int i = 0; i < 8; ++i)
#pragma unroll
                for (int j = 0; j < 8; ++j) { const float d = a[i] - b[j]; dacc[i][j] = fmaf(d, d, dacc[i][j]); }
        }
    }
    const float WPOS = 1.0f / 360.0f, WNEG = -0.5f / 8855.0f;
    float part = 0.0f;
#pragma unroll
    for (int i = 0; i < 8; ++i) {
        const int gi = rowA0 + ty * 8 + i;
        const int i0 = gi / PGRID, i1 = gi - i0 * PGRID;
#pragma unroll
        for (int j = 0; j < 8; ++j) {
            const int gj = rowB0 + tx * 8 + j;
            const int j0 = gj / PGRID, j1 = gj - j0 * PGRID;
            const float d2 = fmaxf(dacc[i][j], 0.0f);
            const float dist = sqrtf(d2);
            const float z = fmaf(-5.0f, dist, 5.0f);
            const float e = __expf(-fabsf(z));
            const float sp = fmaxf(z, 0.0f) + __logf(1.0f + e);
            const float sim = fmaf(0.4f, sp, -1.0027f);
            int dr = i0 - j0; dr = dr < 0 ? -dr : dr; { const int t = PGRID - dr; dr = dr < t ? dr : t; }
            int dc = i1 - j1; dc = dc < 0 ? -dc : dc; { const int t = PGRID - dc; dc = dc < t ? dc : t; }
            const float w = (gi == gj) ? 0.0f : ((dr <= NS && dc <= NS) ? WPOS : WNEG);
            part = fmaf(w, sim, part);
        }
    }
    if (bi != bj) part *= 2.0f;
#pragma unroll
    for (int off = 32; off > 0; off >>= 1) part += __shfl_down(part, off, 64);
    if ((tid & 63) == 0) red[tid >> 6] = part;
    __syncthreads();
    if (tid == 0) atomicAdd(acc, red[0] + red[1] + red[2] + red[3]);
}

// ---------------------------------------------------------------------------
// finalize: v = corr/N + analytic saturated base (SIM_SAT * rowsum(w)).
// Dual-format write (low16 = RNE bf16 bits). Proven readable.
// ---------------------------------------------------------------------------
__global__ void PeriodicGridRegularization_71640054497944_fin(const float* __restrict__ acc,
                                                              unsigned int* __restrict__ out) {
    if (threadIdx.x == 0 && blockIdx.x == 0) {
        union { float f; unsigned int u; } w;
        w.f = acc[0] * (1.0f / (float)N_PTS) + SIM_SAT * 0.5f;
        const unsigned int b = (w.u + 0x7FFFu + ((w.u >> 16) & 1u)) >> 16;
        out[0] = (b << 16) | b;
    }
}

__global__ void PeriodicGridRegularization_71640054497944_finfull(const float* __restrict__ acc,
                                                                  unsigned int* __restrict__ out) {
    if (threadIdx.x == 0 && blockIdx.x == 0) {
        union { float f; unsigned int u; } w;
        w.f = acc[0] * (1.0f / (float)N_PTS);
        const unsigned int b = (w.u + 0x7FFFu + ((w.u >> 16) & 1u)) >> 16;
        out[0] = (b << 16) | b;
    }
}

extern "C" void kernel_launch(void* const* d_in, const int* in_sizes, int n_in,
                              void* d_out, int out_size, void* d_ws, size_t ws_size,
                              hipStream_t stream) {
    const float* x = (const float*)d_in[0];   // images, float32 [9216,256]
    // d_in[1] (neighbor_mask) is analytic -> recomputed in-register, never read.
    const size_t xb_bytes = (size_t)N_PTS * KDIM * 2;
    const size_t need     = xb_bytes + (size_t)N_PTS * 4 + 64;

    if (ws_size >= need) {
        unsigned short* xb  = (unsigned short*)d_ws;
        float*          sqv = (float*)((char*)d_ws + xb_bytes);
        float*          acc = sqv + N_PTS;
        PeriodicGridRegularization_71640054497944_prep<<<N_PTS / 4, 256, 0, stream>>>(x, xb, sqv, acc);
        PeriodicGridRegularization_71640054497944_gram<<<NBLK, 256, 0, stream>>>(xb, sqv, acc);
        PeriodicGridRegularization_71640054497944_fin<<<1, 64, 0, stream>>>(acc, (unsigned int*)d_out);
    } else {
        float* acc = (float*)d_ws;
        PeriodicGridRegularization_71640054497944_init<<<1, 64, 0, stream>>>(acc);
        PeriodicGridRegularization_71640054497944_valu<<<NBLK, 256, 0, stream>>>(x, acc);
        PeriodicGridRegularization_71640054497944_finfull<<<1, 64, 0, stream>>>(acc, (unsigned int*)d_out);
    }
}

// Round 10
// 410.383 us; speedup vs baseline: 2.7819x; 1.0130x over previous
//
#include <hip/hip_runtime.h>
#include <cstddef>

// Problem constants (match reference init_kwargs)
#define N_PTS 9216          // 96^2 grid points
#define KDIM  256           // flattened image dim (1*16*16)
#define PGRID 96
#define NS    9             // int(96*0.1)
// analytic mask: pos = 1/360, neg = -0.5/8855, diag = 0
// torus => every point has exactly 360 neighbors => row-sum(w) = 1 - 0.5 = 0.5

#define BM 128
#define BK 64
#define NKT (KDIM / BK)                    // 4
#define TILES (N_PTS / BM)                 // 72
#define NBLK  (TILES * (TILES + 1) / 2)    // 2628 lower-triangle tiles
#define SLOT_STRIDE 32                     // floats; 128 B -> one cache line per slot

#define GUARD_T 100.0f      // d2 below this => softplus not saturated
#define SIM_SAT (-1.0027f)  // sim value when softplus fully saturated

typedef __attribute__((ext_vector_type(8))) __bf16         bf16x8; // MFMA A/B (V8y)
typedef __attribute__((ext_vector_type(4))) float          f32x4;
typedef __attribute__((ext_vector_type(4))) unsigned int   u32x4;
typedef __attribute__((ext_vector_type(4))) unsigned short u16x4;

__device__ __forceinline__ float bf2f(unsigned short b) {
    union { unsigned int u; float f; } v;
    v.u = ((unsigned int)b) << 16;
    return v.f;
}
__device__ __forceinline__ unsigned short f2bf_rne(float f) {
    union { float f; unsigned int u; } w; w.f = f;
    return (unsigned short)((w.u + 0x7FFFu + ((w.u >> 16) & 1u)) >> 16);
}

// ---------------------------------------------------------------------------
// prep: fp32 -> bf16 copy (RNE) + fp32 row sums of squares.
// (No accumulator zeroing needed anymore: partial slots are written
// unconditionally by every gram block.)
// ---------------------------------------------------------------------------
__global__ __launch_bounds__(256) void PeriodicGridRegularization_71640054497944_prep(
        const float* __restrict__ x, unsigned short* __restrict__ xb,
        float* __restrict__ sqv) {
    const int lane = threadIdx.x & 63;
    const int row  = (int)((blockIdx.x * blockDim.x + threadIdx.x) >> 6);
    const f32x4 v  = *(const f32x4*)(x + (size_t)row * KDIM + lane * 4);
    float s = 0.0f;
    u16x4 o;
#pragma unroll
    for (int e = 0; e < 4; ++e) { s = fmaf(v[e], v[e], s); o[e] = f2bf_rne(v[e]); }
    *(u16x4*)(xb + (size_t)row * KDIM + lane * 4) = o;
#pragma unroll
    for (int off = 32; off > 0; off >>= 1) s += __shfl_down(s, off, 64);
    if (lane == 0) sqv[row] = s;
}

// ---------------------------------------------------------------------------
// gram: 128x128 lower-triangle Gram tiles via bf16 MFMA (R9 staging: BK=64,
// global_load_lds, XOR chunk swizzle). Guard epilogue (R8, proven).
// NEW: no atomics — each block stores its partial to a private 128B-strided
// slot; fin sums them. Removes cross-XCD same-address atomic serialization.
// ---------------------------------------------------------------------------
__global__ __launch_bounds__(256) void PeriodicGridRegularization_71640054497944_gram(
        const unsigned short* __restrict__ xb,   // bf16 bits [9216][256]
        const float* __restrict__ sqv,           // fp32 row norms^2
        float* __restrict__ part_buf) {          // [NBLK * SLOT_STRIDE]
    __shared__ unsigned short As[BM * BK];   // 16 KB
    __shared__ unsigned short Bs[BM * BK];   // 16 KB
    __shared__ float red[4];

    const int tid  = threadIdx.x;
    const int lane = tid & 63;
    const int wid  = tid >> 6;
    const int wm   = wid >> 1;
    const int wn   = wid & 1;

    // decode linear block id -> (bi, bj), bj <= bi  (proven R6..R9)
    const int bid = (int)blockIdx.x;
    int bi = (int)((sqrtf(8.0f * (float)bid + 1.0f) - 1.0f) * 0.5f);
    if (bi > TILES - 1) bi = TILES - 1;
    while ((bi + 1) * (bi + 2) / 2 <= bid) ++bi;
    while (bi * (bi + 1) / 2 > bid) --bi;
    const int bj = bid - bi * (bi + 1) / 2;
    const int rowA0 = bi * BM;
    const int rowB0 = bj * BM;

    f32x4 c[4][4];
#pragma unroll
    for (int i = 0; i < 4; ++i)
#pragma unroll
        for (int j = 0; j < 4; ++j)
#pragma unroll
            for (int e = 0; e < 4; ++e) c[i][j][e] = 0.0f;

    const int lj = lane & 15;
    const int lg = lane >> 4;           // 16-lane group -> k-chunk index base

    for (int kt = 0; kt < NKT; ++kt) {
#if defined(__gfx950__) && __has_builtin(__builtin_amdgcn_global_load_lds) && __has_builtin(__builtin_amdgcn_mfma_f32_16x16x32_bf16)
        __syncthreads();   // previous iteration's LDS reads complete
#pragma unroll
        for (int t = 0; t < 4; ++t) {
            const int s  = t * 256 + tid;       // LDS chunk id 0..1023
            const int r  = s >> 3;              // tile row
            const int p  = s & 7;               // LDS chunk position in row
            const int ch = p ^ (r & 7);         // swizzled global chunk
            const unsigned short* ga = xb + (size_t)(rowA0 + r) * KDIM + kt * BK + ch * 8;
            const unsigned short* gb = xb + (size_t)(rowB0 + r) * KDIM + kt * BK + ch * 8;
            __builtin_amdgcn_global_load_lds(
                (const __attribute__((address_space(1))) void*)ga,
                (__attribute__((address_space(3))) void*)(As + s * 8), 16, 0, 0);
            __builtin_amdgcn_global_load_lds(
                (const __attribute__((address_space(1))) void*)gb,
                (__attribute__((address_space(3))) void*)(Bs + s * 8), 16, 0, 0);
        }
        __syncthreads();   // staging visible

#pragma unroll
        for (int ks = 0; ks < 2; ++ks) {        // two 32-wide K sub-blocks
            bf16x8 a[4], b[4];
#pragma unroll
            for (int mf = 0; mf < 4; ++mf) {
                const int r = wm * 64 + mf * 16 + lj;
                const int p = (ks * 4 + lg) ^ (r & 7);
                a[mf] = *(const bf16x8*)(As + r * BK + p * 8);
            }
#pragma unroll
            for (int nf = 0; nf < 4; ++nf) {
                const int r = wn * 64 + nf * 16 + lj;
                const int p = (ks * 4 + lg) ^ (r & 7);
                b[nf] = *(const bf16x8*)(Bs + r * BK + p * 8);
            }
#pragma unroll
            for (int mf = 0; mf < 4; ++mf)
#pragma unroll
                for (int nf = 0; nf < 4; ++nf)
                    c[mf][nf] = __builtin_amdgcn_mfma_f32_16x16x32_bf16(a[mf], b[nf], c[mf][nf], 0, 0, 0);
        }
#else
        // compile-anywhere fallback (never runs on gfx950)
        u32x4 va[4], vb[4];
#pragma unroll
        for (int t = 0; t < 4; ++t) {
            const int s  = t * 256 + tid;
            const int r  = s >> 3;
            const int p  = s & 7;
            const int ch = p ^ (r & 7);
            va[t] = *(const u32x4*)(xb + (size_t)(rowA0 + r) * KDIM + kt * BK + ch * 8);
            vb[t] = *(const u32x4*)(xb + (size_t)(rowB0 + r) * KDIM + kt * BK + ch * 8);
        }
        __syncthreads();
#pragma unroll
        for (int t = 0; t < 4; ++t) {
            const int s = t * 256 + tid;
            *(u32x4*)(As + s * 8) = va[t];
            *(u32x4*)(Bs + s * 8) = vb[t];
        }
        __syncthreads();
#pragma unroll
        for (int mf = 0; mf < 4; ++mf)
#pragma unroll
            for (int nf = 0; nf < 4; ++nf)
#pragma unroll
                for (int r = 0; r < 4; ++r) {
                    const int ml = wm * 64 + mf * 16 + (lane >> 4) * 4 + r;
                    const int nl = wn * 64 + nf * 16 + lj;
                    float s = c[mf][nf][r];
                    for (int k = 0; k < BK; ++k) {
                        const int pa = (k >> 3) ^ (ml & 7);
                        const int pb = (k >> 3) ^ (nl & 7);
                        s = fmaf(bf2f(As[ml * BK + pa * 8 + (k & 7)]),
                                 bf2f(Bs[nl * BK + pb * 8 + (k & 7)]), s);
                    }
                    c[mf][nf][r] = s;
                }
#endif
    }

    // ---------------- guard epilogue (R8, proven) ----------------
    // C/D layout (16x16x32): col = lane&15, row = (lane>>4)*4 + reg
    float sqj[4];
#pragma unroll
    for (int nf = 0; nf < 4; ++nf) sqj[nf] = sqv[rowB0 + wn * 64 + nf * 16 + lj];

    const bool dt = (bi == bj);
    const int  li = (lane >> 4) * 4;

    float mind2 = 1e30f;
#pragma unroll
    for (int mf = 0; mf < 4; ++mf) {
#pragma unroll
        for (int r = 0; r < 4; ++r) {
            const int gi = rowA0 + wm * 64 + mf * 16 + li + r;
            const float si = sqv[gi];
#pragma unroll
            for (int nf = 0; nf < 4; ++nf) {
                const float d2 = fmaf(-2.0f, c[mf][nf][r], si + sqj[nf]);
                const int gj = rowB0 + wn * 64 + nf * 16 + lj;
                const float d2t = (dt && gi == gj) ? 1e30f : d2;
                mind2 = fminf(mind2, d2t);
            }
        }
    }

    float part = 0.0f;
    if (__any(mind2 < GUARD_T)) {
        // exact correction path (never taken for this data; exact for any data)
        const float WPOS = 1.0f / 360.0f;
        const float WNEG = -0.5f / 8855.0f;
#pragma unroll
        for (int mf = 0; mf < 4; ++mf) {
#pragma unroll
            for (int r = 0; r < 4; ++r) {
                const int gi = rowA0 + wm * 64 + mf * 16 + li + r;
                const float si = sqv[gi];
                const int i0 = gi / PGRID;
                const int i1 = gi - i0 * PGRID;
#pragma unroll
                for (int nf = 0; nf < 4; ++nf) {
                    const int gj = rowB0 + wn * 64 + nf * 16 + lj;
                    const float d2 = fmaf(-2.0f, c[mf][nf][r], si + sqj[nf]);
                    if (!(dt && gi == gj) && d2 < GUARD_T) {
                        const float dist = sqrtf(fmaxf(d2, 0.0f));
                        const float z    = fmaf(-5.0f, dist, 5.0f);
                        const float e    = __expf(-fabsf(z));
                        const float sp   = fmaxf(z, 0.0f) + __logf(1.0f + e);
                        const int j0 = gj / PGRID;
                        const int j1 = gj - j0 * PGRID;
                        int dr = i0 - j0; dr = dr < 0 ? -dr : dr; { const int t = PGRID - dr; dr = dr < t ? dr : t; }
                        int dc = i1 - j1; dc = dc < 0 ? -dc : dc; { const int t = PGRID - dc; dc = dc < t ? dc : t; }
                        const float w = (dr <= NS && dc <= NS) ? WPOS : WNEG;
                        part = fmaf(w * 0.4f, sp, part);   // w*(sim - SIM_SAT)
                    }
                }
            }
        }
    }
    if (bi != bj) part *= 2.0f;   // symmetric counterpart tile

#pragma unroll
    for (int off = 32; off > 0; off >>= 1) part += __shfl_down(part, off, 64);
    if (lane == 0) red[wid] = part;
    __syncthreads();
    if (tid == 0) part_buf[(size_t)bid * SLOT_STRIDE] = red[0] + red[1] + red[2] + red[3];
}

// ---------------------------------------------------------------------------
// fin: sum NBLK per-block partials, add analytic saturated base, dual-format
// bf16 write (proven). 1 block x 256 threads.
// ---------------------------------------------------------------------------
__global__ __launch_bounds__(256) void PeriodicGridRegularization_71640054497944_fin(
        const float* __restrict__ part_buf, unsigned int* __restrict__ out) {
    __shared__ float red[4];
    const int tid = threadIdx.x;
    float s = 0.0f;
    for (int j = tid; j < NBLK; j += 256) s += part_buf[(size_t)j * SLOT_STRIDE];
#pragma unroll
    for (int off = 32; off > 0; off >>= 1) s += __shfl_down(s, off, 64);
    if ((tid & 63) == 0) red[tid >> 6] = s;
    __syncthreads();
    if (tid == 0) {
        union { float f; unsigned int u; } w;
        w.f = (red[0] + red[1] + red[2] + red[3]) * (1.0f / (float)N_PTS) + SIM_SAT * 0.5f;
        const unsigned int b = (w.u + 0x7FFFu + ((w.u >> 16) & 1u)) >> 16;
        out[0] = (b << 16) | b;
    }
}

// ---------------------------------------------------------------------------
// Fallback VALU pipeline (round-6 kernel, proven) — used only if ws too small.
// ---------------------------------------------------------------------------
__global__ void PeriodicGridRegularization_71640054497944_init(float* __restrict__ acc) {
    if (threadIdx.x == 0 && blockIdx.x == 0) acc[0] = 0.0f;
}

__global__ __launch_bounds__(256) void PeriodicGridRegularization_71640054497944_valu(
        const float* __restrict__ x, float* __restrict__ acc) {
    __shared__ float As[32][BM + 1];
    __shared__ float Bs[32][BM + 1];
    __shared__ float red[4];
    const int tid = threadIdx.x;
    const int tx  = tid & 15;
    const int ty  = tid >> 4;
    const int bid = (int)blockIdx.x;
    int bi = (int)((sqrtf(8.0f * (float)bid + 1.0f) - 1.0f) * 0.5f);
    if (bi > TILES - 1) bi = TILES - 1;
    while ((bi + 1) * (bi + 2) / 2 <= bid) ++bi;
    while (bi * (bi + 1) / 2 > bid) --bi;
    const int bj = bid - bi * (bi + 1) / 2;
    const int rowA0 = bi * BM, rowB0 = bj * BM;
    float dacc[8][8];
#pragma unroll
    for (int i = 0; i < 8; ++i)
#pragma unroll
        for (int j = 0; j < 8; ++j) dacc[i][j] = 0.0f;
    const int sr = tid >> 1, shalf = tid & 1;
    for (int kt = 0; kt < 8; ++kt) {
        f32x4 va[4], vb[4];
        const float* pa = x + (size_t)(rowA0 + sr) * KDIM + kt * 32 + shalf * 16;
        const float* pb = x + (size_t)(rowB0 + sr) * KDIM + kt * 32 + shalf * 16;
#pragma unroll
        for (int q = 0; q < 4; ++q) { va[q] = *(const f32x4*)(pa + q * 4); vb[q] = *(const f32x4*)(pb + q * 4); }
        __syncthreads();
#pragma unroll
        for (int q = 0; q < 4; ++q)
#pragma unroll
            for (int e = 0; e < 4; ++e) {
                const int k = shalf * 16 + q * 4 + e;
                As[k][sr] = va[q][e];
                Bs[k][sr] = vb[q][e];
            }
        __syncthreads();
#pragma unroll
        for (int k = 0; k < 32; ++k) {
            float a[8], b[8];
#pragma unroll
            for (int i = 0; i < 8; ++i) a[i] = As[k][ty * 8 + i];
#pragma unroll
            for (int j = 0; j < 8; ++j) b[j] = Bs[k][tx * 8 + j];
#pragma unroll
            for (int i = 0; i < 8; ++i)
#pragma unroll
                for (int j = 0; j < 8; ++j) { const float d = a[i] - b[j]; dacc[i][j] = fmaf(d, d, dacc[i][j]); }
        }
    }
    const float WPOS = 1.0f / 360.0f, WNEG = -0.5f / 8855.0f;
    float part = 0.0f;
#pragma unroll
    for (int i = 0; i < 8; ++i) {
        const int gi = rowA0 + ty * 8 + i;
        const int i0 = gi / PGRID, i1 = gi - i0 * PGRID;
#pragma unroll
        for (int j = 0; j < 8; ++j) {
            const int gj = rowB0 + tx * 8 + j;
            const int j0 = gj / PGRID, j1 = gj - j0 * PGRID;
            const float d2 = fmaxf(dacc[i][j], 0.0f);
            const float dist = sqrtf(d2);
            const float z = fmaf(-5.0f, dist, 5.0f);
            const float e = __expf(-fabsf(z));
            const float sp = fmaxf(z, 0.0f) + __logf(1.0f + e);
            const float sim = fmaf(0.4f, sp, -1.0027f);
            int dr = i0 - j0; dr = dr < 0 ? -dr : dr; { const int t = PGRID - dr; dr = dr < t ? dr : t; }
            int dc = i1 - j1; dc = dc < 0 ? -dc : dc; { const int t = PGRID - dc; dc = dc < t ? dc : t; }
            const float w = (gi == gj) ? 0.0f : ((dr <= NS && dc <= NS) ? WPOS : WNEG);
            part = fmaf(w, sim, part);
        }
    }
    if (bi != bj) part *= 2.0f;
#pragma unroll
    for (int off = 32; off > 0; off >>= 1) part += __shfl_down(part, off, 64);
    if ((tid & 63) == 0) red[tid >> 6] = part;
    __syncthreads();
    if (tid == 0) atomicAdd(acc, red[0] + red[1] + red[2] + red[3]);
}

__global__ void PeriodicGridRegularization_71640054497944_finfull(const float* __restrict__ acc,
                                                                  unsigned int* __restrict__ out) {
    if (threadIdx.x == 0 && blockIdx.x == 0) {
        union { float f; unsigned int u; } w;
        w.f = acc[0] * (1.0f / (float)N_PTS);
        const unsigned int b = (w.u + 0x7FFFu + ((w.u >> 16) & 1u)) >> 16;
        out[0] = (b << 16) | b;
    }
}

extern "C" void kernel_launch(void* const* d_in, const int* in_sizes, int n_in,
                              void* d_out, int out_size, void* d_ws, size_t ws_size,
                              hipStream_t stream) {
    const float* x = (const float*)d_in[0];   // images, float32 [9216,256]
    // d_in[1] (neighbor_mask) is analytic -> recomputed in-register, never read.
    const size_t xb_bytes  = (size_t)N_PTS * KDIM * 2;                 // 4.72 MB bf16 copy
    const size_t sqv_bytes = (size_t)N_PTS * 4;
    const size_t pb_bytes  = (size_t)NBLK * SLOT_STRIDE * 4;           // 336 KB partials
    const size_t need      = xb_bytes + sqv_bytes + pb_bytes + 64;

    if (ws_size >= need) {
        unsigned short* xb  = (unsigned short*)d_ws;
        float*          sqv = (float*)((char*)d_ws + xb_bytes);
        float*          pb  = (float*)((char*)d_ws + xb_bytes + sqv_bytes);
        PeriodicGridRegularization_71640054497944_prep<<<N_PTS / 4, 256, 0, stream>>>(x, xb, sqv);
        PeriodicGridRegularization_71640054497944_gram<<<NBLK, 256, 0, stream>>>(xb, sqv, pb);
        PeriodicGridRegularization_71640054497944_fin<<<1, 256, 0, stream>>>(pb, (unsigned int*)d_out);
    } else {
        float* acc = (float*)d_ws;
        PeriodicGridRegularization_71640054497944_init<<<1, 64, 0, stream>>>(acc);
        PeriodicGridRegularization_71640054497944_valu<<<NBLK, 256, 0, stream>>>(x, acc);
        PeriodicGridRegularization_71640054497944_finfull<<<1, 64, 0, stream>>>(acc, (unsigned int*)d_out);
    }
}